// Round 4
// baseline (160.991 us; speedup 1.0000x reference)
//
#include <hip/hip_runtime.h>
#include <stdint.h>

#define NTOK 65536
#define G 4
#define K 1024
#define C 64
#define GC 256
#define ROWS_PER_BLOCK 512          // 8 waves x 64 rows
#define R 4                         // 16-row tiles per wave
#define NBLK ((NTOK / ROWS_PER_BLOCK) * G)   // 512 blocks, 2/CU

typedef float floatx4 __attribute__((ext_vector_type(4)));
typedef long  longx2  __attribute__((ext_vector_type(2)));

__device__ __forceinline__ uint32_t pk4_fp8(float a, float b, float c, float d) {
    uint32_t v = (uint32_t)__builtin_amdgcn_cvt_pk_fp8_f32(a, b, 0, false);
    v = (uint32_t)__builtin_amdgcn_cvt_pk_fp8_f32(c, d, (int)v, true);
    return v;
}

// Block-resident fp8 codebook (64 KB LDS), barrier-free main loop.
// Score' = 512 - K*(z . e)  (positive) ; low 10 bits carry code id for packed argmin.
__global__ __launch_bounds__(512, 4)
void vq_main(const float* __restrict__ z, const float* __restrict__ emb,
             float* __restrict__ out, float* __restrict__ partial) {
    __shared__ long Ecode[8192];    // [kt<64][lane<64][s<2] u64 = 64 KB, A-frag swizzled
    __shared__ float wl[8];

    const int t    = (int)threadIdx.x;
    const int g    = (int)blockIdx.x & 3;
    const int nb   = (int)blockIdx.x >> 2;
    const int wave = t >> 6;
    const int lane = t & 63;
    const int q    = lane >> 4;
    const int lr   = lane & 15;
    const int n0   = nb * ROWS_PER_BLOCK + wave * 64;

    // ---- codebook: f32 -> fp8(e4m3), scaled by -K, swizzled into LDS ----
    {
        const int kt = t >> 3;          // code tile 0..63
        const int s  = (t >> 2) & 1;    // k-step
        const int qq = t & 3;           // k-quad
        const float* src = emb + ((size_t)(g * K + kt * 16)) * C + s * 32 + qq * 8;
#pragma unroll
        for (int ii = 0; ii < 16; ++ii) {
            const int i = (ii + qq * 4) & 15;           // stagger LDS banks
            floatx4 a = *(const floatx4*)(src + i * C);
            floatx4 b = *(const floatx4*)(src + i * C + 4);
            uint32_t lo = pk4_fp8(-1024.f * a[0], -1024.f * a[1], -1024.f * a[2], -1024.f * a[3]);
            uint32_t hi = pk4_fp8(-1024.f * b[0], -1024.f * b[1], -1024.f * b[2], -1024.f * b[3]);
            Ecode[kt * 128 + (qq * 16 + i) * 2 + s] = (long)(((uint64_t)hi << 32) | (uint64_t)lo);
        }
    }

    // ---- z fragments: B-operand fp8, 4 row-tiles x 2 k-steps, in regs ----
    long zf[R][2];
#pragma unroll
    for (int r = 0; r < R; ++r) {
        const float* zp = z + (size_t)(n0 + r * 16 + lr) * GC + g * C + q * 8;
#pragma unroll
        for (int s = 0; s < 2; ++s) {
            floatx4 a = *(const floatx4*)(zp + s * 32);
            floatx4 b = *(const floatx4*)(zp + s * 32 + 4);
            uint32_t lo = pk4_fp8(a[0], a[1], a[2], a[3]);
            uint32_t hi = pk4_fp8(b[0], b[1], b[2], b[3]);
            zf[r][s] = (long)(((uint64_t)hi << 32) | (uint64_t)lo);
        }
    }

    __syncthreads();     // only barrier before the scan

    float best[R];
#pragma unroll
    for (int r = 0; r < R; ++r) best[r] = 3.4e38f;
    int vki[4];
#pragma unroll
    for (int j = 0; j < 4; ++j) vki[j] = q * 4 + j;

    const floatx4 BIAS = {512.f, 512.f, 512.f, 512.f};

#pragma unroll 4
    for (int kt = 0; kt < 64; ++kt) {
        longx2 e = *(const longx2*)&Ecode[kt * 128 + lane * 2];   // ds_read_b128
#pragma unroll
        for (int r = 0; r < R; ++r) {
            floatx4 acc = __builtin_amdgcn_mfma_f32_16x16x32_fp8_fp8(e[0], zf[r][0], BIAS, 0, 0, 0);
            acc = __builtin_amdgcn_mfma_f32_16x16x32_fp8_fp8(e[1], zf[r][1], acc, 0, 0, 0);
            uint32_t p0 = (__float_as_uint(acc[0]) & 0xFFFFFC00u) | (uint32_t)vki[0];
            uint32_t p1 = (__float_as_uint(acc[1]) & 0xFFFFFC00u) | (uint32_t)vki[1];
            uint32_t p2 = (__float_as_uint(acc[2]) & 0xFFFFFC00u) | (uint32_t)vki[2];
            uint32_t p3 = (__float_as_uint(acc[3]) & 0xFFFFFC00u) | (uint32_t)vki[3];
            float m01 = fminf(__uint_as_float(p0), __uint_as_float(p1));
            float m23 = fminf(__uint_as_float(p2), __uint_as_float(p3));
            best[r] = fminf(best[r], fminf(m01, m23));
        }
#pragma unroll
        for (int j = 0; j < 4; ++j) vki[j] += 16;
    }

    // ---- cross-lane argmin, exact-f32 gather + loss + output ----
    float lsum = 0.0f;
#pragma unroll
    for (int r = 0; r < R; ++r) {
        float bv = best[r];
        bv = fminf(bv, __shfl_xor(bv, 16, 64));
        bv = fminf(bv, __shfl_xor(bv, 32, 64));
        const int ki = (int)(__float_as_uint(bv) & 1023u);
        const int row = n0 + r * 16 + lr;
        const float* ep = emb + ((size_t)(g * K + ki)) * C + q * 16;
        const float* zp = z + (size_t)row * GC + g * C + q * 16;
        float*       op = out + (size_t)row * GC + g * C + q * 16;
#pragma unroll
        for (int u = 0; u < 4; ++u) {
            floatx4 e  = *(const floatx4*)(ep + u * 4);
            floatx4 zz = *(const floatx4*)(zp + u * 4);
            *(floatx4*)(op + u * 4) = e;
            floatx4 d = e - zz;
            lsum += d[0] * d[0] + d[1] * d[1] + d[2] * d[2] + d[3] * d[3];
        }
    }
#pragma unroll
    for (int off = 1; off < 64; off <<= 1) lsum += __shfl_xor(lsum, off, 64);
    if (lane == 0) wl[wave] = lsum;
    __syncthreads();
    if (t == 0) {
        float s = 0.0f;
#pragma unroll
        for (int w = 0; w < 8; ++w) s += wl[w];
        partial[blockIdx.x] = s;
    }
}

__global__ __launch_bounds__(512)
void vq_fin(const float* __restrict__ partial, float* __restrict__ out) {
    __shared__ float wl[8];
    float s = partial[threadIdx.x];
#pragma unroll
    for (int off = 1; off < 64; off <<= 1) s += __shfl_xor(s, off, 64);
    const int wave = (int)threadIdx.x >> 6;
    if ((threadIdx.x & 63) == 0) wl[wave] = s;
    __syncthreads();
    if (threadIdx.x == 0) {
        float tot = 0.0f;
#pragma unroll
        for (int w = 0; w < 8; ++w) tot += wl[w];
        out[(size_t)NTOK * GC] = tot * (1.5f / ((float)NTOK * (float)GC));
    }
}

extern "C" void kernel_launch(void* const* d_in, const int* in_sizes, int n_in,
                              void* d_out, int out_size, void* d_ws, size_t ws_size,
                              hipStream_t stream) {
    const float* z   = (const float*)d_in[0];
    const float* emb = (const float*)d_in[1];
    float* out = (float*)d_out;
    float* partial = (float*)d_ws;   // 512 floats

    vq_main<<<dim3(NBLK), dim3(512), 0, stream>>>(z, emb, out, partial);
    vq_fin<<<dim3(1), dim3(512), 0, stream>>>(partial, out);
}

// Round 5
// 160.950 us; speedup vs baseline: 1.0002x; 1.0002x over previous
//
#include <hip/hip_runtime.h>
#include <stdint.h>

#define NTOK 65536
#define G 4
#define K 1024
#define C 64
#define GC 256
#define WAVES 16                    // 1024 threads/block
#define R 2                         // 16-row tiles per wave -> 32 rows/wave
#define ROWS_PER_BLOCK (WAVES * R * 16)          // 512
#define NBLK ((NTOK / ROWS_PER_BLOCK) * G)       // 512 blocks, 2/CU resident

typedef float floatx4 __attribute__((ext_vector_type(4)));
typedef long  longx2  __attribute__((ext_vector_type(2)));

__device__ __forceinline__ uint32_t pk4_fp8(float a, float b, float c, float d) {
    uint32_t v = (uint32_t)__builtin_amdgcn_cvt_pk_fp8_f32(a, b, 0, false);
    v = (uint32_t)__builtin_amdgcn_cvt_pk_fp8_f32(c, d, (int)v, true);
    return v;
}

// Block-resident fp8 codebook (64 KB LDS), 16-wave blocks -> 32 waves/CU.
// Score' = 512 - 1024*(z . e) > 0 ; low 10 bits carry code id (packed argmin).
__global__ __launch_bounds__(1024, 8)   // 8 waves/EU => 2 blocks/CU; caps VGPR at 64
void vq_main(const float* __restrict__ z, const float* __restrict__ emb,
             float* __restrict__ out, float* __restrict__ partial) {
    __shared__ alignas(16) long Ecode[8192];   // [kt<64][lane<64][s<2] u64 = 64 KB
    __shared__ float wl[WAVES];

    const int t    = (int)threadIdx.x;
    const int g    = (int)blockIdx.x & 3;
    const int nb   = (int)blockIdx.x >> 2;
    const int wave = t >> 6;
    const int lane = t & 63;
    const int q    = lane >> 4;
    const int lr   = lane & 15;
    const int n0   = nb * ROWS_PER_BLOCK + wave * (R * 16);

    // ---- codebook: f32 -> fp8(e4m3) scaled by -1024, A-frag layout, conflict-free ----
    {
        const int l   = t & 63;          // lds lane slot
        const int lq  = l >> 4;
        const int llr = l & 15;
        const int kt0 = t >> 6;          // 0..15
#pragma unroll
        for (int i = 0; i < 4; ++i) {
            const int kt = kt0 + 16 * i;
            const float* src = emb + ((size_t)(g * K + kt * 16 + llr)) * C + lq * 8;
            floatx4 a0 = *(const floatx4*)(src);
            floatx4 a1 = *(const floatx4*)(src + 4);
            floatx4 b0 = *(const floatx4*)(src + 32);
            floatx4 b1 = *(const floatx4*)(src + 36);
            uint32_t w0 = pk4_fp8(-1024.f * a0[0], -1024.f * a0[1], -1024.f * a0[2], -1024.f * a0[3]);
            uint32_t w1 = pk4_fp8(-1024.f * a1[0], -1024.f * a1[1], -1024.f * a1[2], -1024.f * a1[3]);
            uint32_t w2 = pk4_fp8(-1024.f * b0[0], -1024.f * b0[1], -1024.f * b0[2], -1024.f * b0[3]);
            uint32_t w3 = pk4_fp8(-1024.f * b1[0], -1024.f * b1[1], -1024.f * b1[2], -1024.f * b1[3]);
            longx2 v;
            v[0] = (long)(((uint64_t)w1 << 32) | (uint64_t)w0);   // dims q*8..+8
            v[1] = (long)(((uint64_t)w3 << 32) | (uint64_t)w2);   // dims 32+q*8..+8
            *(longx2*)&Ecode[kt * 128 + l * 2] = v;               // ds_write_b128, lane*16B
        }
    }

    // ---- z fragments: B-operand fp8, 2 row-tiles x 2 k-steps, in regs ----
    long zf[R][2];
#pragma unroll
    for (int r = 0; r < R; ++r) {
        const float* zp = z + (size_t)(n0 + r * 16 + lr) * GC + g * C + q * 8;
#pragma unroll
        for (int s = 0; s < 2; ++s) {
            floatx4 a = *(const floatx4*)(zp + s * 32);
            floatx4 b = *(const floatx4*)(zp + s * 32 + 4);
            uint32_t lo = pk4_fp8(a[0], a[1], a[2], a[3]);
            uint32_t hi = pk4_fp8(b[0], b[1], b[2], b[3]);
            zf[r][s] = (long)(((uint64_t)hi << 32) | (uint64_t)lo);
        }
    }

    __syncthreads();     // codebook staged; no barriers in the scan

    float best[R];
#pragma unroll
    for (int r = 0; r < R; ++r) best[r] = 3.4e38f;
    int vki[4];
#pragma unroll
    for (int j = 0; j < 4; ++j) vki[j] = q * 4 + j;

    const floatx4 BIAS = {512.f, 512.f, 512.f, 512.f};

#pragma unroll 4
    for (int kt = 0; kt < 64; ++kt) {
        longx2 e = *(const longx2*)&Ecode[kt * 128 + lane * 2];   // ds_read_b128
#pragma unroll
        for (int r = 0; r < R; ++r) {
            floatx4 acc = __builtin_amdgcn_mfma_f32_16x16x32_fp8_fp8(e[0], zf[r][0], BIAS, 0, 0, 0);
            acc = __builtin_amdgcn_mfma_f32_16x16x32_fp8_fp8(e[1], zf[r][1], acc, 0, 0, 0);
            float p0 = __uint_as_float((__float_as_uint(acc[0]) & 0xFFFFFC00u) | (uint32_t)vki[0]);
            float p1 = __uint_as_float((__float_as_uint(acc[1]) & 0xFFFFFC00u) | (uint32_t)vki[1]);
            float p2 = __uint_as_float((__float_as_uint(acc[2]) & 0xFFFFFC00u) | (uint32_t)vki[2]);
            float p3 = __uint_as_float((__float_as_uint(acc[3]) & 0xFFFFFC00u) | (uint32_t)vki[3]);
            float m012 = fminf(fminf(p0, p1), p2);                 // v_min3
            best[r] = fminf(fminf(m012, p3), best[r]);             // v_min3
        }
#pragma unroll
        for (int j = 0; j < 4; ++j) vki[j] += 16;
    }

    // ---- cross-lane argmin, exact-f32 gather + loss + output ----
    float lsum = 0.0f;
#pragma unroll
    for (int r = 0; r < R; ++r) {
        float bv = best[r];
        bv = fminf(bv, __shfl_xor(bv, 16, 64));
        bv = fminf(bv, __shfl_xor(bv, 32, 64));
        const int ki = (int)(__float_as_uint(bv) & 1023u);
        const int row = n0 + r * 16 + lr;
        const float* ep = emb + ((size_t)(g * K + ki)) * C + q * 16;
        const float* zp = z + (size_t)row * GC + g * C + q * 16;
        float*       op = out + (size_t)row * GC + g * C + q * 16;
#pragma unroll
        for (int u = 0; u < 4; ++u) {
            floatx4 e  = *(const floatx4*)(ep + u * 4);
            floatx4 zz = *(const floatx4*)(zp + u * 4);
            *(floatx4*)(op + u * 4) = e;
            floatx4 d = e - zz;
            lsum += d[0] * d[0] + d[1] * d[1] + d[2] * d[2] + d[3] * d[3];
        }
    }
#pragma unroll
    for (int off = 1; off < 64; off <<= 1) lsum += __shfl_xor(lsum, off, 64);
    if (lane == 0) wl[wave] = lsum;
    __syncthreads();
    if (t == 0) {
        float s = 0.0f;
#pragma unroll
        for (int w = 0; w < WAVES; ++w) s += wl[w];
        partial[blockIdx.x] = s;
    }
}

__global__ __launch_bounds__(512)
void vq_fin(const float* __restrict__ partial, float* __restrict__ out) {
    __shared__ float wl[8];
    float s = partial[threadIdx.x];
#pragma unroll
    for (int off = 1; off < 64; off <<= 1) s += __shfl_xor(s, off, 64);
    const int wave = (int)threadIdx.x >> 6;
    if ((threadIdx.x & 63) == 0) wl[wave] = s;
    __syncthreads();
    if (threadIdx.x == 0) {
        float tot = 0.0f;
#pragma unroll
        for (int w = 0; w < 8; ++w) tot += wl[w];
        out[(size_t)NTOK * GC] = tot * (1.5f / ((float)NTOK * (float)GC));
    }
}

extern "C" void kernel_launch(void* const* d_in, const int* in_sizes, int n_in,
                              void* d_out, int out_size, void* d_ws, size_t ws_size,
                              hipStream_t stream) {
    const float* z   = (const float*)d_in[0];
    const float* emb = (const float*)d_in[1];
    float* out = (float*)d_out;
    float* partial = (float*)d_ws;   // 512 floats

    vq_main<<<dim3(NBLK), dim3(1024), 0, stream>>>(z, emb, out, partial);
    vq_fin<<<dim3(1), dim3(512), 0, stream>>>(partial, out);
}